// Round 1
// baseline (460.480 us; speedup 1.0000x reference)
//
#include <hip/hip_runtime.h>
#include <hip/hip_bf16.h>

#define NNODES 100000
#define NEDGES 1600000
#define IN_C   256
#define OUT_C  128

// ---------------------------------------------------------------------------
// GEMM: H = X @ W^T.  X:[N,256] f32 row-major, W:[128,256] f32 row-major.
// Tile: 64 rows x 128 cols, BK=64. Block 256 threads, thread tile 4x8.
// ---------------------------------------------------------------------------
__global__ __launch_bounds__(256) void gemm_xwt(const float* __restrict__ X,
                                                const float* __restrict__ W,
                                                float* __restrict__ H) {
    __shared__ float Xs[64 * 68];    // [row][k], stride 68 (pad: 2-way only)
    __shared__ float Ws[128 * 64];   // [o][k], k4 XOR-swizzled by (o>>3)

    const int tid = threadIdx.x;
    const int tx  = tid & 15;        // col group -> cols tx*8 .. +7
    const int ty  = tid >> 4;        // row group -> rows ty*4 .. +3
    const int row0 = blockIdx.x * 64;

    float acc[4][8];
#pragma unroll
    for (int r = 0; r < 4; ++r)
#pragma unroll
        for (int c = 0; c < 8; ++c) acc[r][c] = 0.f;

    for (int kc = 0; kc < IN_C; kc += 64) {
        // stage X tile: 64 rows x 64 k = 1024 float4, 4 per thread
#pragma unroll
        for (int p = 0; p < 4; ++p) {
            int i  = p * 256 + tid;      // 0..1023
            int r  = i >> 4;
            int k4 = i & 15;
            int grow = row0 + r;
            float4 v = make_float4(0.f, 0.f, 0.f, 0.f);
            if (grow < NNODES)
                v = *(const float4*)(X + (size_t)grow * IN_C + kc + k4 * 4);
            *(float4*)(Xs + r * 68 + k4 * 4) = v;
        }
        // stage W tile: 128 o x 64 k = 2048 float4, 8 per thread (swizzled)
#pragma unroll
        for (int p = 0; p < 8; ++p) {
            int i  = p * 256 + tid;      // 0..2047
            int o  = i >> 4;
            int k4 = i & 15;
            float4 v = *(const float4*)(W + (size_t)o * IN_C + kc + k4 * 4);
            *(float4*)(Ws + o * 64 + ((k4 ^ (o >> 3)) & 15) * 4) = v;
        }
        __syncthreads();

#pragma unroll
        for (int k4 = 0; k4 < 16; ++k4) {
            float4 xr[4];
#pragma unroll
            for (int r = 0; r < 4; ++r)
                xr[r] = *(const float4*)(Xs + (ty * 4 + r) * 68 + k4 * 4);
#pragma unroll
            for (int cc = 0; cc < 8; ++cc) {
                int o = tx * 8 + cc;
                float4 w = *(const float4*)(Ws + o * 64 + ((k4 ^ tx) & 15) * 4);
#pragma unroll
                for (int r = 0; r < 4; ++r) {
                    acc[r][cc] += xr[r].x * w.x + xr[r].y * w.y
                                + xr[r].z * w.z + xr[r].w * w.w;
                }
            }
        }
        __syncthreads();
    }

    // epilogue: coalesced float4 stores
#pragma unroll
    for (int r = 0; r < 4; ++r) {
        int grow = row0 + ty * 4 + r;
        if (grow < NNODES) {
            float4 v0 = make_float4(acc[r][0], acc[r][1], acc[r][2], acc[r][3]);
            float4 v1 = make_float4(acc[r][4], acc[r][5], acc[r][6], acc[r][7]);
            *(float4*)(H + (size_t)grow * OUT_C + tx * 8)     = v0;
            *(float4*)(H + (size_t)grow * OUT_C + tx * 8 + 4) = v1;
        }
    }
}

// ---------------------------------------------------------------------------
// rowptr[r] = lower_bound(A_rows, r)  (A_rows sorted).  r in [0, N].
// ---------------------------------------------------------------------------
__global__ __launch_bounds__(256) void build_rowptr(const int* __restrict__ rows,
                                                    int* __restrict__ rowptr) {
    int r = blockIdx.x * 256 + threadIdx.x;
    if (r > NNODES) return;
    int lo = 0, hi = NEDGES;
    while (lo < hi) {
        int mid = (lo + hi) >> 1;
        if (rows[mid] < r) lo = mid + 1; else hi = mid;
    }
    rowptr[r] = lo;
}

// ---------------------------------------------------------------------------
// SpMM: out[r,:] = sum_e vals[e] * H[cols[e],:] over e in [rowptr[r],rowptr[r+1])
// One wave per row, 2 channels per lane (128 ch / 64 lanes).
// ---------------------------------------------------------------------------
__global__ __launch_bounds__(256) void spmm_rows(const float* __restrict__ H,
                                                 const int* __restrict__ rowptr,
                                                 const int* __restrict__ cols,
                                                 const float* __restrict__ vals,
                                                 float* __restrict__ out) {
    const int wid  = threadIdx.x >> 6;
    const int lane = threadIdx.x & 63;
    const int row  = blockIdx.x * 4 + wid;
    if (row >= NNODES) return;

    const int s = rowptr[row];
    const int e = rowptr[row + 1];

    float a0 = 0.f, a1 = 0.f;
    for (int i = s; i < e; ++i) {
        int   c = cols[i];
        float v = vals[i];
        const float* hrow = H + (size_t)c * OUT_C;
        a0 += v * hrow[lane];
        a1 += v * hrow[lane + 64];
    }
    out[(size_t)row * OUT_C + lane]      = a0;
    out[(size_t)row * OUT_C + lane + 64] = a1;
}

// ---------------------------------------------------------------------------
extern "C" void kernel_launch(void* const* d_in, const int* in_sizes, int n_in,
                              void* d_out, int out_size, void* d_ws, size_t ws_size,
                              hipStream_t stream) {
    const float* X      = (const float*)d_in[0];
    const float* W      = (const float*)d_in[1];
    const int*   A_rows = (const int*)d_in[2];
    const int*   A_cols = (const int*)d_in[3];
    const float* A_vals = (const float*)d_in[4];
    float* out = (float*)d_out;

    float* H      = (float*)d_ws;                                   // 51.2 MB
    int*   rowptr = (int*)((char*)d_ws +
                           (size_t)NNODES * OUT_C * sizeof(float)); // +400 KB

    gemm_xwt<<<(NNODES + 63) / 64, 256, 0, stream>>>(X, W, H);
    build_rowptr<<<(NNODES + 1 + 255) / 256, 256, 0, stream>>>(A_rows, rowptr);
    spmm_rows<<<(NNODES + 3) / 4, 256, 0, stream>>>(H, rowptr, A_cols, A_vals, out);
}

// Round 2
// 118.574 us; speedup vs baseline: 3.8835x; 3.8835x over previous
//
#include <hip/hip_runtime.h>
#include <hip/hip_bf16.h>

#define NNODES 100000
#define NEDGES 1600000
#define IN_C   256
#define OUT_C  128

typedef short bf16x8 __attribute__((ext_vector_type(8)));
typedef float f32x4  __attribute__((ext_vector_type(4)));

static __device__ __forceinline__ unsigned short f2bf(float f) {
    union { float f; unsigned u; } c; c.f = f;
    unsigned r = c.u + 0x7fffu + ((c.u >> 16) & 1u);   // round-to-nearest-even
    return (unsigned short)(r >> 16);
}
static __device__ __forceinline__ float bflo(unsigned u) {
    union { unsigned u; float f; } c; c.u = u << 16; return c.f;
}
static __device__ __forceinline__ float bfhi(unsigned u) {
    union { unsigned u; float f; } c; c.u = u & 0xffff0000u; return c.f;
}

// ---------------------------------------------------------------------------
// GEMM: H(bf16) = X @ W^T.  X:[N,256] f32, W:[128,256] f32.
// Tile 128x128, BK=128, 4 waves (2x2), mfma_f32_16x16x32_bf16.
// LDS tiles XOR-swizzled: byte ^= (row&7)<<4  -> ds_read_b128 2-way (free).
// ---------------------------------------------------------------------------
__global__ __launch_bounds__(256) void gemm_xwt(const float* __restrict__ X,
                                                const float* __restrict__ W,
                                                unsigned short* __restrict__ H) {
    __shared__ unsigned short Xs[128 * 128];   // bf16 bits, [row][k], swizzled
    __shared__ unsigned short Wsh[128 * 128];  // bf16 bits, [o][k], swizzled

    const int tid  = threadIdx.x;
    const int lane = tid & 63;
    const int wid  = tid >> 6;
    const int wr   = (wid >> 1) * 64;          // wave row offset in tile
    const int wc   = (wid & 1) * 64;           // wave col offset in tile
    const int row0 = blockIdx.x * 128;

    f32x4 acc[4][4] = {};

    for (int kc = 0; kc < IN_C; kc += 128) {
        // stage X tile: 128 rows x 128 k (f32 -> bf16)
#pragma unroll
        for (int p = 0; p < 16; ++p) {
            int idx = p * 256 + tid;           // 0..4095
            int r   = idx >> 5;                // row 0..127
            int c4  = idx & 31;                // float4 column
            float4 v = make_float4(0.f, 0.f, 0.f, 0.f);
            int grow = row0 + r;
            if (grow < NNODES)
                v = *(const float4*)(X + (size_t)grow * IN_C + kc + c4 * 4);
            int byte = (r * 256 + c4 * 8) ^ ((r & 7) << 4);
            *(ushort4*)((char*)Xs + byte) =
                make_ushort4(f2bf(v.x), f2bf(v.y), f2bf(v.z), f2bf(v.w));
        }
        // stage W tile: 128 o x 128 k
#pragma unroll
        for (int p = 0; p < 16; ++p) {
            int idx = p * 256 + tid;
            int o   = idx >> 5;
            int c4  = idx & 31;
            float4 v = *(const float4*)(W + (size_t)o * IN_C + kc + c4 * 4);
            int byte = (o * 256 + c4 * 8) ^ ((o & 7) << 4);
            *(ushort4*)((char*)Wsh + byte) =
                make_ushort4(f2bf(v.x), f2bf(v.y), f2bf(v.z), f2bf(v.w));
        }
        __syncthreads();

#pragma unroll
        for (int ks = 0; ks < 4; ++ks) {
            const int kb = ks * 64 + (lane >> 4) * 16;   // byte offset of k-slice
            bf16x8 a[4], b[4];
#pragma unroll
            for (int m = 0; m < 4; ++m) {
                int r    = wr + m * 16 + (lane & 15);
                int byte = (r * 256 + kb) ^ ((r & 7) << 4);
                a[m] = *(const bf16x8*)((const char*)Xs + byte);
            }
#pragma unroll
            for (int n = 0; n < 4; ++n) {
                int o    = wc + n * 16 + (lane & 15);
                int byte = (o * 256 + kb) ^ ((o & 7) << 4);
                b[n] = *(const bf16x8*)((const char*)Wsh + byte);
            }
#pragma unroll
            for (int m = 0; m < 4; ++m)
#pragma unroll
                for (int n = 0; n < 4; ++n)
                    acc[m][n] = __builtin_amdgcn_mfma_f32_16x16x32_bf16(
                        a[m], b[n], acc[m][n], 0, 0, 0);
        }
        __syncthreads();
    }

    // epilogue: C/D layout col=lane&15, row=(lane>>4)*4+reg
#pragma unroll
    for (int m = 0; m < 4; ++m) {
#pragma unroll
        for (int r = 0; r < 4; ++r) {
            int grow = row0 + wr + m * 16 + (lane >> 4) * 4 + r;
            if (grow < NNODES) {
#pragma unroll
                for (int n = 0; n < 4; ++n) {
                    int col = wc + n * 16 + (lane & 15);
                    H[(size_t)grow * OUT_C + col] = f2bf(acc[m][n][r]);
                }
            }
        }
    }
}

// ---------------------------------------------------------------------------
// rowptr[r] = lower_bound(A_rows, r)  (A_rows sorted).  r in [0, N].
// ---------------------------------------------------------------------------
__global__ __launch_bounds__(256) void build_rowptr(const int* __restrict__ rows,
                                                    int* __restrict__ rowptr) {
    int r = blockIdx.x * 256 + threadIdx.x;
    if (r > NNODES) return;
    int lo = 0, hi = NEDGES;
    while (lo < hi) {
        int mid = (lo + hi) >> 1;
        if (rows[mid] < r) lo = mid + 1; else hi = mid;
    }
    rowptr[r] = lo;
}

// ---------------------------------------------------------------------------
// SpMM: out[r,:] = sum_e vals[e] * H[cols[e],:].  One wave per row.
// H is bf16: lane loads 1 dword = 2 channels. 4-edge ILP unroll.
// ---------------------------------------------------------------------------
__global__ __launch_bounds__(256) void spmm_rows(const unsigned* __restrict__ H32,
                                                 const int* __restrict__ rowptr,
                                                 const int* __restrict__ cols,
                                                 const float* __restrict__ vals,
                                                 float* __restrict__ out) {
    const int wid  = threadIdx.x >> 6;
    const int lane = threadIdx.x & 63;
    const int row  = blockIdx.x * 4 + wid;
    if (row >= NNODES) return;

    const int s = rowptr[row];
    const int e = rowptr[row + 1];

    float a0 = 0.f, a1 = 0.f;
    int i = s;
    for (; i + 4 <= e; i += 4) {
        int   c0 = cols[i],     c1 = cols[i + 1], c2 = cols[i + 2], c3 = cols[i + 3];
        float v0 = vals[i],     v1 = vals[i + 1], v2 = vals[i + 2], v3 = vals[i + 3];
        unsigned u0 = H32[(size_t)c0 * 64 + lane];
        unsigned u1 = H32[(size_t)c1 * 64 + lane];
        unsigned u2 = H32[(size_t)c2 * 64 + lane];
        unsigned u3 = H32[(size_t)c3 * 64 + lane];
        a0 += v0 * bflo(u0) + v1 * bflo(u1) + v2 * bflo(u2) + v3 * bflo(u3);
        a1 += v0 * bfhi(u0) + v1 * bfhi(u1) + v2 * bfhi(u2) + v3 * bfhi(u3);
    }
    for (; i < e; ++i) {
        int c = cols[i]; float v = vals[i];
        unsigned u = H32[(size_t)c * 64 + lane];
        a0 += v * bflo(u); a1 += v * bfhi(u);
    }
    *(float2*)(out + (size_t)row * OUT_C + lane * 2) = make_float2(a0, a1);
}

// ---------------------------------------------------------------------------
extern "C" void kernel_launch(void* const* d_in, const int* in_sizes, int n_in,
                              void* d_out, int out_size, void* d_ws, size_t ws_size,
                              hipStream_t stream) {
    const float* X      = (const float*)d_in[0];
    const float* W      = (const float*)d_in[1];
    const int*   A_rows = (const int*)d_in[2];
    const int*   A_cols = (const int*)d_in[3];
    const float* A_vals = (const float*)d_in[4];
    float* out = (float*)d_out;

    unsigned short* H   = (unsigned short*)d_ws;                    // 25.6 MB bf16
    int* rowptr = (int*)((char*)d_ws +
                         (size_t)NNODES * OUT_C * sizeof(unsigned short));

    gemm_xwt<<<(NNODES + 127) / 128, 256, 0, stream>>>(X, W, H);
    build_rowptr<<<(NNODES + 1 + 255) / 256, 256, 0, stream>>>(A_rows, rowptr);
    spmm_rows<<<(NNODES + 3) / 4, 256, 0, stream>>>((const unsigned*)H, rowptr,
                                                    A_cols, A_vals, out);
}

// Round 3
// 107.763 us; speedup vs baseline: 4.2731x; 1.1003x over previous
//
#include <hip/hip_runtime.h>
#include <hip/hip_bf16.h>

#define NNODES 100000
#define NEDGES 1600000
#define IN_C   256
#define OUT_C  128

typedef short bf16x8 __attribute__((ext_vector_type(8)));
typedef float f32x4  __attribute__((ext_vector_type(4)));

static __device__ __forceinline__ unsigned short f2bf(float f) {
    union { float f; unsigned u; } c; c.f = f;
    unsigned r = c.u + 0x7fffu + ((c.u >> 16) & 1u);   // round-to-nearest-even
    return (unsigned short)(r >> 16);
}
static __device__ __forceinline__ float bflo(unsigned u) {
    union { unsigned u; float f; } c; c.u = u << 16; return c.f;
}
static __device__ __forceinline__ float bfhi(unsigned u) {
    union { unsigned u; float f; } c; c.u = u & 0xffff0000u; return c.f;
}

// ---------------------------------------------------------------------------
// GEMM: H(bf16) = X @ W^T.  X:[N,256] f32, W:[128,256] f32.
// Tile 128x128, BK=128, 4 waves (2x2), mfma_f32_16x16x32_bf16.
// LDS tiles XOR-swizzled: byte ^= (row&7)<<4  -> ds_read_b128 2-way (free).
// ---------------------------------------------------------------------------
__global__ __launch_bounds__(256) void gemm_xwt(const float* __restrict__ X,
                                                const float* __restrict__ W,
                                                unsigned short* __restrict__ H) {
    __shared__ unsigned short Xs[128 * 128];   // bf16 bits, [row][k], swizzled
    __shared__ unsigned short Wsh[128 * 128];  // bf16 bits, [o][k], swizzled

    const int tid  = threadIdx.x;
    const int lane = tid & 63;
    const int wid  = tid >> 6;
    const int wr   = (wid >> 1) * 64;          // wave row offset in tile
    const int wc   = (wid & 1) * 64;           // wave col offset in tile
    const int row0 = blockIdx.x * 128;

    f32x4 acc[4][4] = {};

    for (int kc = 0; kc < IN_C; kc += 128) {
        // stage X tile: 128 rows x 128 k (f32 -> bf16)
#pragma unroll
        for (int p = 0; p < 16; ++p) {
            int idx = p * 256 + tid;           // 0..4095
            int r   = idx >> 5;                // row 0..127
            int c4  = idx & 31;                // float4 column
            float4 v = make_float4(0.f, 0.f, 0.f, 0.f);
            int grow = row0 + r;
            if (grow < NNODES)
                v = *(const float4*)(X + (size_t)grow * IN_C + kc + c4 * 4);
            int byte = (r * 256 + c4 * 8) ^ ((r & 7) << 4);
            *(ushort4*)((char*)Xs + byte) =
                make_ushort4(f2bf(v.x), f2bf(v.y), f2bf(v.z), f2bf(v.w));
        }
        // stage W tile: 128 o x 128 k
#pragma unroll
        for (int p = 0; p < 16; ++p) {
            int idx = p * 256 + tid;
            int o   = idx >> 5;
            int c4  = idx & 31;
            float4 v = *(const float4*)(W + (size_t)o * IN_C + kc + c4 * 4);
            int byte = (o * 256 + c4 * 8) ^ ((o & 7) << 4);
            *(ushort4*)((char*)Wsh + byte) =
                make_ushort4(f2bf(v.x), f2bf(v.y), f2bf(v.z), f2bf(v.w));
        }
        __syncthreads();

#pragma unroll
        for (int ks = 0; ks < 4; ++ks) {
            const int kb = ks * 64 + (lane >> 4) * 16;   // byte offset of k-slice
            bf16x8 a[4], b[4];
#pragma unroll
            for (int m = 0; m < 4; ++m) {
                int r    = wr + m * 16 + (lane & 15);
                int byte = (r * 256 + kb) ^ ((r & 7) << 4);
                a[m] = *(const bf16x8*)((const char*)Xs + byte);
            }
#pragma unroll
            for (int n = 0; n < 4; ++n) {
                int o    = wc + n * 16 + (lane & 15);
                int byte = (o * 256 + kb) ^ ((o & 7) << 4);
                b[n] = *(const bf16x8*)((const char*)Wsh + byte);
            }
#pragma unroll
            for (int m = 0; m < 4; ++m)
#pragma unroll
                for (int n = 0; n < 4; ++n)
                    acc[m][n] = __builtin_amdgcn_mfma_f32_16x16x32_bf16(
                        a[m], b[n], acc[m][n], 0, 0, 0);
        }
        __syncthreads();
    }

    // epilogue: C/D layout col=lane&15, row=(lane>>4)*4+reg
#pragma unroll
    for (int m = 0; m < 4; ++m) {
#pragma unroll
        for (int r = 0; r < 4; ++r) {
            int grow = row0 + wr + m * 16 + (lane >> 4) * 4 + r;
            if (grow < NNODES) {
#pragma unroll
                for (int n = 0; n < 4; ++n) {
                    int col = wc + n * 16 + (lane & 15);
                    H[(size_t)grow * OUT_C + col] = f2bf(acc[m][n][r]);
                }
            }
        }
    }
}

// ---------------------------------------------------------------------------
// rowptr[r] = lower_bound(A_rows, r)  (A_rows sorted).  r in [0, N].
// ---------------------------------------------------------------------------
__global__ __launch_bounds__(256) void build_rowptr(const int* __restrict__ rows,
                                                    int* __restrict__ rowptr) {
    int r = blockIdx.x * 256 + threadIdx.x;
    if (r > NNODES) return;
    int lo = 0, hi = NEDGES;
    while (lo < hi) {
        int mid = (lo + hi) >> 1;
        if (rows[mid] < r) lo = mid + 1; else hi = mid;
    }
    rowptr[r] = lo;
}

// ---------------------------------------------------------------------------
// SpMM: out[r,:] = sum_e vals[e] * H[cols[e],:].  One wave per row.
// 16 lanes per edge (uint4 = 8 bf16 ch/lane), 4 edges per load instruction,
// 16-edge unroll -> 4 dwordx4 gathers in flight. cols/vals preloaded per
// 64-edge chunk, broadcast via shfl. Final shfl_xor(16/32) reduction.
// ---------------------------------------------------------------------------
__global__ __launch_bounds__(256) void spmm_rows(const uint4* __restrict__ H4,
                                                 const int* __restrict__ rowptr,
                                                 const int* __restrict__ cols,
                                                 const float* __restrict__ vals,
                                                 float* __restrict__ out) {
    const int wid  = threadIdx.x >> 6;
    const int lane = threadIdx.x & 63;
    const int row  = blockIdx.x * 4 + wid;
    if (row >= NNODES) return;

    const int s  = rowptr[row];
    const int e  = rowptr[row + 1];
    const int g  = lane >> 4;      // edge subgroup 0..3
    const int cg = lane & 15;      // channel group: channels cg*8 .. cg*8+7

    float acc[8];
#pragma unroll
    for (int t = 0; t < 8; ++t) acc[t] = 0.f;

    for (int base = s; base < e; base += 64) {
        const int cnt = (e - base < 64) ? (e - base) : 64;
        int   ec = 0;
        float ev = 0.f;
        if (lane < cnt) { ec = cols[base + lane]; ev = vals[base + lane]; }

        int j = 0;
        // main: 16 edges per iteration -> 4 independent 16B gathers in flight
        for (; j + 16 <= cnt; j += 16) {
#pragma unroll
            for (int q = 0; q < 4; ++q) {
                int   c = __shfl(ec, j + q * 4 + g);
                float v = __shfl(ev, j + q * 4 + g);
                uint4 u = H4[(size_t)c * 16 + cg];
                acc[0] += v * bflo(u.x); acc[1] += v * bfhi(u.x);
                acc[2] += v * bflo(u.y); acc[3] += v * bfhi(u.y);
                acc[4] += v * bflo(u.z); acc[5] += v * bfhi(u.z);
                acc[6] += v * bflo(u.w); acc[7] += v * bfhi(u.w);
            }
        }
        // tail: 4 edges at a time (overshoot lanes have ev=0 -> contribute 0)
        for (; j < cnt; j += 4) {
            int   c = __shfl(ec, j + g);
            float v = __shfl(ev, j + g);
            uint4 u = H4[(size_t)c * 16 + cg];
            acc[0] += v * bflo(u.x); acc[1] += v * bfhi(u.x);
            acc[2] += v * bflo(u.y); acc[3] += v * bfhi(u.y);
            acc[4] += v * bflo(u.z); acc[5] += v * bfhi(u.z);
            acc[6] += v * bflo(u.w); acc[7] += v * bfhi(u.w);
        }
    }

    // reduce across the 4 edge subgroups (lanes cg, cg+16, cg+32, cg+48)
#pragma unroll
    for (int t = 0; t < 8; ++t) {
        acc[t] += __shfl_xor(acc[t], 16);
        acc[t] += __shfl_xor(acc[t], 32);
    }
    if (lane < 16) {
        float4 v0 = make_float4(acc[0], acc[1], acc[2], acc[3]);
        float4 v1 = make_float4(acc[4], acc[5], acc[6], acc[7]);
        *(float4*)(out + (size_t)row * OUT_C + cg * 8)     = v0;
        *(float4*)(out + (size_t)row * OUT_C + cg * 8 + 4) = v1;
    }
}

// ---------------------------------------------------------------------------
extern "C" void kernel_launch(void* const* d_in, const int* in_sizes, int n_in,
                              void* d_out, int out_size, void* d_ws, size_t ws_size,
                              hipStream_t stream) {
    const float* X      = (const float*)d_in[0];
    const float* W      = (const float*)d_in[1];
    const int*   A_rows = (const int*)d_in[2];
    const int*   A_cols = (const int*)d_in[3];
    const float* A_vals = (const float*)d_in[4];
    float* out = (float*)d_out;

    unsigned short* H   = (unsigned short*)d_ws;                    // 25.6 MB bf16
    int* rowptr = (int*)((char*)d_ws +
                         (size_t)NNODES * OUT_C * sizeof(unsigned short));

    gemm_xwt<<<(NNODES + 127) / 128, 256, 0, stream>>>(X, W, H);
    build_rowptr<<<(NNODES + 1 + 255) / 256, 256, 0, stream>>>(A_rows, rowptr);
    spmm_rows<<<(NNODES + 3) / 4, 256, 0, stream>>>((const uint4*)H, rowptr,
                                                    A_cols, A_vals, out);
}